// Round 6
// baseline (4628.837 us; speedup 1.0000x reference)
//
#include <hip/hip_runtime.h>

typedef unsigned short u16;
typedef __bf16 bf16x8 __attribute__((ext_vector_type(8)));
typedef float f32x4 __attribute__((ext_vector_type(4)));
typedef u16 u16x8 __attribute__((ext_vector_type(8)));
typedef u16 u16x4 __attribute__((ext_vector_type(4)));

#define N_FEAT 8192
#define M_MEM 16384
#define C_DIM 1536
#define NBATCH 32
#define NKT 48            // 1536/32 K-tiles (BK=32)
#define NMT 64            // 16384/256 memory tiles
#define FINF 3.4e38f

__device__ __forceinline__ u16 f2bf(float x){           // RTNE fp32->bf16
  unsigned u = __float_as_uint(x);
  u += 0x7fffu + ((u >> 16) & 1u);
  return (u16)(u >> 16);
}
__device__ __forceinline__ float bf2f(u16 h){
  return __uint_as_float(((unsigned)h) << 16);
}

#define GLDS16(g, l) __builtin_amdgcn_global_load_lds( \
    (const __attribute__((address_space(1))) void*)(g), \
    (__attribute__((address_space(3))) void*)(l), 16, 0, 0)

// ---------------------------------------------------------------------------
// 1) fp32 -> bf16 copy + exact fp32 row norms. 1 wave per row, 4 rows/block.
// ---------------------------------------------------------------------------
__global__ __launch_bounds__(256) void conv_norm_k(const float* __restrict__ in,
                                                   u16* __restrict__ ob,
                                                   float* __restrict__ nrm){
  int row  = blockIdx.x*4 + (threadIdx.x>>6);
  int lane = threadIdx.x & 63;
  const float* r = in + (size_t)row*C_DIM;
  u16* o = ob + (size_t)row*C_DIM;
  float s = 0.f;
  #pragma unroll
  for (int i=0;i<6;++i){
    int idx = i*256 + lane*4;
    float4 v = *(const float4*)(r + idx);
    s += v.x*v.x + v.y*v.y + v.z*v.z + v.w*v.w;
    u16x4 u; u.x=f2bf(v.x); u.y=f2bf(v.y); u.z=f2bf(v.z); u.w=f2bf(v.w);
    *(u16x4*)(o + idx) = u;
  }
  #pragma unroll
  for (int m=32;m;m>>=1) s += __shfl_xor(s, m);
  if (lane==0) nrm[row] = s;
}

// ---------------------------------------------------------------------------
// 2) 256x256 bf16 MFMA distance + fused per-row min/argmin per tile.
//    BK=32 -> LDS 64 KiB -> 2 blocks/CU: cross-block HW wave overlap fills
//    the DS/MFMA pipes (m114 mechanism) instead of intra-block scheduling.
//    8 waves (2Mx4N); per K-tile: 12 ds_read_b128 + 32 MFMA, 2 barriers,
//    4x global_load_lds prefetch (kt+2), counted vmcnt(4).
// ---------------------------------------------------------------------------
__global__ __launch_bounds__(512, 4) void dist256_k(const u16* __restrict__ fb,
                                                    const u16* __restrict__ mb,
                                                    const float* __restrict__ fn,
                                                    const float* __restrict__ mn,
                                                    float* __restrict__ pmin,
                                                    int* __restrict__ pidx){
  __shared__ u16 lds[32768];          // 64 KiB: 2 bufs x (A 8K + B 8K u16)
  const int tid = threadIdx.x;
  const int bid = blockIdx.x;
  // XCD-aware 2D remap: co-resident 64 blocks/XCD = 8 nt x 8 mt rectangle.
  const int xcd = bid & 7;
  const int li  = bid >> 3;                     // 0..255 within XCD
  const int nt  = ((li >> 5) << 2) | (li & 3);  // 0..31 feature tile
  const int mt  = (xcd << 3) | ((li >> 2) & 7); // 0..63 memory tile
  const int wid = tid >> 6, lane = tid & 63;
  const int wm = wid >> 2, wn = wid & 3;        // 2x4 waves, each 128x64 out
  const int lr = lane & 15, lk = lane >> 4;
  const int slk8 = (lk ^ ((lr >> 1) & 3)) * 8;  // swizzled read chunk (u16 units)
  const int sgc  = (tid & 3) ^ ((tid >> 3) & 3);// pre-swizzled source chunk
  const int arow0 = nt*256, brow0 = mt*256;

  // u16-unit LDS offsets: buf stride 16384, B at +8192, h-half at +4096
#define ISSUE_A(kt, h, bb) GLDS16( \
    fb + (size_t)(arow0 + (h)*128 + (tid>>2))*C_DIM + (kt)*32 + sgc*8, \
    lds + (bb)*16384 + (h)*4096 + tid*8)
#define ISSUE_B(kt, h, bb) GLDS16( \
    mb + (size_t)(brow0 + (h)*128 + (tid>>2))*C_DIM + (kt)*32 + sgc*8, \
    lds + (bb)*16384 + 8192 + (h)*4096 + tid*8)
#define LDA(bo, row) (*(const bf16x8*)(lds + (bo) + (row)*32 + slk8))
#define LDB(bo, row) (*(const bf16x8*)(lds + (bo) + 8192 + (row)*32 + slk8))
#define BAR()   __builtin_amdgcn_s_barrier()

  f32x4 acc[8][4];
  #pragma unroll
  for (int m=0;m<8;++m)
    #pragma unroll
    for (int n=0;n<4;++n) acc[m][n] = (f32x4){0.f,0.f,0.f,0.f};

  // prologue: K-tiles 0 (buf0) and 1 (buf1); wait K-tile 0 landed.
  ISSUE_A(0,0,0); ISSUE_A(0,1,0); ISSUE_B(0,0,0); ISSUE_B(0,1,0);
  ISSUE_A(1,0,1); ISSUE_A(1,1,1); ISSUE_B(1,0,1); ISSUE_B(1,1,1);
  asm volatile("s_waitcnt vmcnt(4)" ::: "memory");
  BAR();

  for (int u=0; u<NKT; ++u){
    const int b  = u & 1;
    const int bo = b*16384;
    const int ktn = (u+2 < NKT) ? u+2 : NKT-1;  // tail: harmless dummy reload
    bf16x8 av[8], bv[4];
    #pragma unroll
    for (int n=0;n<4;++n) bv[n] = LDB(bo, wn*64 + n*16 + lr);
    #pragma unroll
    for (int m=0;m<8;++m) av[m] = LDA(bo, wm*128 + m*16 + lr);
    __builtin_amdgcn_s_setprio(1);
    #pragma unroll
    for (int m=0;m<8;++m)
      #pragma unroll
      for (int n=0;n<4;++n)
        acc[m][n] = __builtin_amdgcn_mfma_f32_16x16x32_bf16(av[m], bv[n], acc[m][n],0,0,0);
    __builtin_amdgcn_s_setprio(0);

    BAR();                              // all waves' reads of buf b returned
    ISSUE_A(ktn,0,b); ISSUE_A(ktn,1,b); // prefetch kt u+2 into freed buf b
    ISSUE_B(ktn,0,b); ISSUE_B(ktn,1,b);
    asm volatile("s_waitcnt vmcnt(4)" ::: "memory");  // buf nb (kt u+1) landed
    BAR();
  }

  asm volatile("s_waitcnt vmcnt(0)" ::: "memory");    // drain tail prefetches
  __syncthreads();                                    // before LDS reuse

  // epilogue: d = sqrt(max(fa + mb - 2ab, 0)); min/argmin over 256 cols.
  // C/D frag layout: col = lane&15, row = (lane>>4)*4 + reg
  const int rowbase = nt*256 + wm*128;
  const int colbase = mt*256 + wn*64;
  float mnv[4];
  #pragma unroll
  for (int n=0;n<4;++n) mnv[n] = mn[colbase + n*16 + lr];
  float* smf = (float*)lds;               // [4][256]
  int*   sii = (int*)((char*)lds + 4096); // [4][256]
  #pragma unroll
  for (int m=0;m<8;++m){
    float mv[4]; int mi[4];
    #pragma unroll
    for (int r=0;r<4;++r){
      float fa = fn[rowbase + m*16 + lk*4 + r];
      mv[r] = FINF; mi[r] = 0x7fffffff;
      #pragma unroll
      for (int n=0;n<4;++n){
        int ci = colbase + n*16 + lr;
        float d2 = fa + mnv[n] - 2.0f*acc[m][n][r];
        float d = sqrtf(fmaxf(d2, 0.0f));
        if (d < mv[r]){ mv[r] = d; mi[r] = ci; }
      }
    }
    #pragma unroll
    for (int msk=1; msk<16; msk<<=1){
      #pragma unroll
      for (int r=0;r<4;++r){
        float ov = __shfl_xor(mv[r], msk);
        int   oi = __shfl_xor(mi[r], msk);
        if (ov < mv[r] || (ov == mv[r] && oi < mi[r])){ mv[r]=ov; mi[r]=oi; }
      }
    }
    if (lr == 0){
      #pragma unroll
      for (int r=0;r<4;++r){
        int rl = wm*128 + m*16 + lk*4 + r;
        smf[wn*256 + rl] = mv[r];
        sii[wn*256 + rl] = mi[r];
      }
    }
  }
  __syncthreads();
  if (tid < 256){
    float v = smf[tid]; int idx = sii[tid];
    #pragma unroll
    for (int w=1;w<4;++w){
      float ov = smf[w*256 + tid]; int oi = sii[w*256 + tid];
      if (ov < v || (ov == v && oi < idx)){ v = ov; idx = oi; }
    }
    size_t o = (size_t)(nt*256 + tid)*NMT + mt;
    pmin[o] = v; pidx[o] = idx;
  }
#undef ISSUE_A
#undef ISSUE_B
#undef LDA
#undef LDB
#undef BAR
}

// ---------------------------------------------------------------------------
// 3) refine: exact fp32 distance for candidates within band of bf16 min
//    -> exact nn_dists / nn_indices (selection-exact vs reference).
// ---------------------------------------------------------------------------
__global__ __launch_bounds__(256) void refine_k(const float* __restrict__ feat,
                                                const float* __restrict__ memf,
                                                const float* __restrict__ fn,
                                                const float* __restrict__ mn,
                                                const float* __restrict__ pmin,
                                                const int* __restrict__ pidx,
                                                float* __restrict__ nnd,
                                                int* __restrict__ nni){
  int wid = threadIdx.x>>6, lane = threadIdx.x&63;
  int row = blockIdx.x*4 + wid;
  const float* pm = pmin + (size_t)row*NMT;
  const int*   pi = pidx + (size_t)row*NMT;
  float v0 = pm[lane];
  float mv = v0;
  #pragma unroll
  for (int m=32;m;m>>=1) mv = fminf(mv, __shfl_xor(mv, m));
  float band = mv + 0.02f;   // covers bf16-GEMM error (~16 sigma)
  unsigned long long b0 = __ballot(v0 <= band);

  float fr[24];
  const float* f = feat + (size_t)row*C_DIM;
  #pragma unroll
  for (int i=0;i<6;++i){
    float4 t = *(const float4*)(f + i*256 + lane*4);
    fr[i*4+0]=t.x; fr[i*4+1]=t.y; fr[i*4+2]=t.z; fr[i*4+3]=t.w;
  }
  float fa = fn[row];
  float bd = FINF; int bi = 0x7fffffff;
  while (b0){                       // ascending tile => ascending idx
    int t = __ffsll(b0)-1; b0 &= b0-1;
    int cidx = pi[t];
    const float* mrow = memf + (size_t)cidx*C_DIM;
    float acc = 0.f;
    #pragma unroll
    for (int i=0;i<6;++i){
      float4 m4 = *(const float4*)(mrow + i*256 + lane*4);
      acc += fr[i*4+0]*m4.x + fr[i*4+1]*m4.y + fr[i*4+2]*m4.z + fr[i*4+3]*m4.w;
    }
    #pragma unroll
    for (int m=32;m;m>>=1) acc += __shfl_xor(acc, m);
    float d = sqrtf(fmaxf(fa + mn[cidx] - 2.0f*acc, 0.f));
    if (d < bd || (d == bd && cidx < bi)){ bd = d; bi = cidx; }
  }
  if (lane==0){ nnd[row]=bd; nni[row]=bi; }
}

// ---------------------------------------------------------------------------
// 4) WT[i][y] = composite (gaussian-zero-pad o bilinear-halfpixel) weights
// ---------------------------------------------------------------------------
__global__ void build_WT(float* __restrict__ WT){
  int y = threadIdx.x;                 // 256 threads, 1 block
  float g[25]; float Z = 0.f;
  #pragma unroll
  for (int k=0;k<25;++k){ float x=(float)(k-12)*0.25f; g[k]=expf(-0.5f*x*x); Z+=g[k]; }
  float acc[16];
  #pragma unroll
  for (int i=0;i<16;++i) acc[i]=0.f;
  for (int dy=0; dy<25; ++dy){
    int yy = y - 12 + dy;
    if (yy < 0 || yy > 255) continue;
    float gg = g[dy]/Z;
    float src = ((float)yy + 0.5f)*0.0625f - 0.5f;
    int i0 = (int)floorf(src);
    float fz = src - (float)i0;
    if (i0 < 0){ i0 = 0; fz = 0.f; }
    else if (i0 >= 15){ i0 = 15; fz = 0.f; }
    acc[i0] += gg*(1.f-fz);
    if (fz > 0.f) acc[i0+1] += gg*fz;
  }
  for (int i=0;i<16;++i) WT[i*256 + y] = acc[i];
}

// ---------------------------------------------------------------------------
// 5) amap[b] = W ps[b] W^T  (separable; exact fp32)
// ---------------------------------------------------------------------------
__global__ __launch_bounds__(256) void amap_k(const float* __restrict__ nnd,
                                              const float* __restrict__ WT,
                                              float* __restrict__ out){
  __shared__ float ps[256];
  __shared__ float wt[16*256];
  __shared__ float tmp[16*256];
  int b = blockIdx.x, yc = blockIdx.y, t = threadIdx.x;
  ps[t] = nnd[b*256 + t];
  #pragma unroll
  for (int i=0;i<16;++i) wt[i*256+t] = WT[i*256+t];
  __syncthreads();
  #pragma unroll
  for (int i=0;i<16;++i){
    float s=0.f;
    #pragma unroll
    for (int j=0;j<16;++j) s += wt[j*256+t]*ps[i*16+j];
    tmp[i*256+t]=s;
  }
  __syncthreads();
  float* ob = out + ((size_t)b<<16) + yc*32*256 + t;
  for (int yy=0; yy<32; ++yy){
    int y = yc*32+yy;
    float s=0.f;
    #pragma unroll
    for (int i=0;i<16;++i) s += wt[i*256+y]*tmp[i*256+t];
    ob[(size_t)yy*256] = s;
  }
}

// ---------------------------------------------------------------------------
// 6) per-batch argmax of patch scores -> s_star, m_star_idx
// ---------------------------------------------------------------------------
__global__ void argmax_k(const float* __restrict__ nnd, const int* __restrict__ nni,
                         float* __restrict__ sstar, int* __restrict__ midx){
  int b=blockIdx.x, t=threadIdx.x, lane=t&63, wid=t>>6;
  float v = nnd[b*256+t]; int i=t;
  #pragma unroll
  for (int m=1;m<64;m<<=1){
    float ov=__shfl_xor(v,m); int oi=__shfl_xor(i,m);
    if (ov > v || (ov==v && oi<i)){ v=ov; i=oi; }
  }
  __shared__ float sv[4]; __shared__ int si[4];
  if (lane==0){ sv[wid]=v; si[wid]=i; }
  __syncthreads();
  if (t==0){
    for (int w=1;w<4;++w){ if (sv[w]>v || (sv[w]==v && si[w]<i)){ v=sv[w]; i=si[w]; } }
    sstar[b]=v; midx[b]=nni[b*256+i];
  }
}

// ---------------------------------------------------------------------------
// 7) m_dists: 32 m_star vectors (bf16, half staged in LDS) vs all memory rows
// ---------------------------------------------------------------------------
__global__ __launch_bounds__(256) void mdist_k(const u16* __restrict__ mb,
                                               const float* __restrict__ mn,
                                               const int* __restrict__ midx,
                                               float* __restrict__ dmat){
  __shared__ u16 ms[16*C_DIM];       // 48 KiB: stage 16 m_stars per half
  __shared__ int sidx[32]; __shared__ float snrm[32];
  int t = threadIdx.x;
  if (t < 32){ int r = midx[t]; sidx[t]=r; snrm[t]=mn[r]; }
  int wid=t>>6, lane=t&63;
  for (int h=0; h<2; ++h){
    __syncthreads();
    for (int c=t; c<3072; c+=256){     // 16 rows x 192 x 16B chunks
      int s = c/192, o = c - s*192;
      *(u16x8*)(&ms[s*C_DIM + o*8]) = *(const u16x8*)(mb + (size_t)sidx[h*16+s]*C_DIM + o*8);
    }
    __syncthreads();
    for (int v=0; v<16; ++v){
      int m = blockIdx.x*64 + wid*16 + v;
      const u16* row = mb + (size_t)m*C_DIM;
      float rf[24];
      #pragma unroll
      for (int i=0;i<3;++i){
        u16x8 rv = *(const u16x8*)(row + i*512 + lane*8);
        #pragma unroll
        for (int j=0;j<8;++j) rf[i*8+j] = bf2f(rv[j]);
      }
      float mnv = mn[m];
      for (int s=0;s<16;++s){
        float acc=0.f;
        #pragma unroll
        for (int i=0;i<3;++i){
          u16x8 w = *(const u16x8*)(&ms[s*C_DIM + i*512 + lane*8]);
          #pragma unroll
          for (int j=0;j<8;++j) acc += rf[i*8+j]*bf2f(w[j]);
        }
        #pragma unroll
        for (int msk=32;msk;msk>>=1) acc += __shfl_xor(acc, msk);
        if (lane==0)
          dmat[(size_t)(h*16+s)*M_MEM + m] = sqrtf(fmaxf(snrm[h*16+s] + mnv - 2.0f*acc, 0.f));
      }
    }
  }
}

// ---------------------------------------------------------------------------
// 8) per-batch top-10 smallest distances -> reweighted score
//    (parallel 4-level merge instead of single-thread 2560-scan)
// ---------------------------------------------------------------------------
__device__ __forceinline__ void top10_scan(const float* src, int n, float* tp){
  #pragma unroll
  for (int i=0;i<10;++i) tp[i]=FINF;
  for (int c=0;c<n;++c){
    float v=src[c];
    if (v < tp[9]){
      #pragma unroll
      for (int j=0;j<10;++j){ float lo=fminf(tp[j],v); v=fmaxf(tp[j],v); tp[j]=lo; }
    }
  }
}

__global__ __launch_bounds__(256) void score_k(const float* __restrict__ dmat,
                                               const float* __restrict__ sstar,
                                               float* __restrict__ out){
  int b=blockIdx.x, t=threadIdx.x;
  float top[10];
  #pragma unroll
  for (int i=0;i<10;++i) top[i]=FINF;
  for (int i=0;i<64;++i){
    float v = dmat[(size_t)b*M_MEM + i*256 + t];
    if (v < top[9]){
      #pragma unroll
      for (int j=0;j<10;++j){ float lo=fminf(top[j],v); v=fmaxf(top[j],v); top[j]=lo; }
    }
  }
  __shared__ float cand[2560];
  __shared__ float l1[640];
  __shared__ float l2[160];
  __shared__ float l3[40];
  #pragma unroll
  for (int i=0;i<10;++i) cand[t*10+i]=top[i];
  __syncthreads();
  if (t < 64){
    float tp[10]; top10_scan(&cand[t*40], 40, tp);
    #pragma unroll
    for (int i=0;i<10;++i) l1[t*10+i]=tp[i];
  }
  __syncthreads();
  if (t < 16){
    float tp[10]; top10_scan(&l1[t*40], 40, tp);
    #pragma unroll
    for (int i=0;i<10;++i) l2[t*10+i]=tp[i];
  }
  __syncthreads();
  if (t < 4){
    float tp[10]; top10_scan(&l2[t*40], 40, tp);
    #pragma unroll
    for (int i=0;i<10;++i) l3[t*10+i]=tp[i];
  }
  __syncthreads();
  if (t==0){
    float tp[10]; top10_scan(l3, 40, tp);
    // drop tp[0] (self); w = 1 - exp(d1)/sum = 1 - 1/sum(exp(di-d1))
    float d1 = tp[1];
    float ssum = 0.f;
    #pragma unroll
    for (int i=1;i<10;++i) ssum += expf(tp[i]-d1);
    out[b] = (1.0f - 1.0f/ssum) * sstar[b];
  }
}

// ---------------------------------------------------------------------------
extern "C" void kernel_launch(void* const* d_in, const int* in_sizes, int n_in,
                              void* d_out, int out_size, void* d_ws, size_t ws_size,
                              hipStream_t stream){
  const float* feat = (const float*)d_in[0];
  const float* memf = (const float*)d_in[1];
  float* out = (float*)d_out;
  char* ws = (char*)d_ws;

  size_t o_fb = 0;
  size_t o_mb = o_fb + (size_t)N_FEAT*C_DIM*2;
  size_t o_fn = o_mb + (size_t)M_MEM*C_DIM*2;
  size_t o_mn = o_fn + (size_t)N_FEAT*4;
  size_t o_pv = o_mn + (size_t)M_MEM*4;
  size_t o_pi = o_pv + (size_t)N_FEAT*NMT*4;
  size_t o_nd = o_pi + (size_t)N_FEAT*NMT*4;
  size_t o_ni = o_nd + (size_t)N_FEAT*4;
  size_t o_wt = o_ni + (size_t)N_FEAT*4;
  size_t o_ss = o_wt + (size_t)16*256*4;
  size_t o_mi = o_ss + (size_t)NBATCH*4;
  size_t o_dm = o_mi + (size_t)NBATCH*4;
  size_t need = o_dm + (size_t)NBATCH*M_MEM*4;
  if (ws_size < need) return;

  u16*   fb  = (u16*)(ws+o_fb);
  u16*   mb  = (u16*)(ws+o_mb);
  float* fn  = (float*)(ws+o_fn);
  float* mn  = (float*)(ws+o_mn);
  float* pv  = (float*)(ws+o_pv);
  int*   pi  = (int*)(ws+o_pi);
  float* nd  = (float*)(ws+o_nd);
  int*   ni  = (int*)(ws+o_ni);
  float* wt  = (float*)(ws+o_wt);
  float* ss  = (float*)(ws+o_ss);
  int*   mi  = (int*)(ws+o_mi);
  float* dm  = (float*)(ws+o_dm);

  conv_norm_k<<<N_FEAT/4, 256, 0, stream>>>(feat, fb, fn);
  conv_norm_k<<<M_MEM/4, 256, 0, stream>>>(memf, mb, mn);
  dist256_k<<<2048, 512, 0, stream>>>(fb, mb, fn, mn, pv, pi);
  refine_k<<<N_FEAT/4, 256, 0, stream>>>(feat, memf, fn, mn, pv, pi, nd, ni);
  build_WT<<<1, 256, 0, stream>>>(wt);
  argmax_k<<<NBATCH, 256, 0, stream>>>(nd, ni, ss, mi);
  mdist_k<<<M_MEM/64, 256, 0, stream>>>(mb, mn, mi, dm);
  amap_k<<<dim3(NBATCH, 8), 256, 0, stream>>>(nd, wt, out + 32);
  score_k<<<NBATCH, 256, 0, stream>>>(dm, ss, out);
}

// Round 7
// 929.722 us; speedup vs baseline: 4.9787x; 4.9787x over previous
//
#include <hip/hip_runtime.h>

typedef unsigned short u16;
typedef __bf16 bf16x8 __attribute__((ext_vector_type(8)));
typedef float f32x4 __attribute__((ext_vector_type(4)));
typedef u16 u16x8 __attribute__((ext_vector_type(8)));
typedef u16 u16x4 __attribute__((ext_vector_type(4)));

#define N_FEAT 8192
#define M_MEM 16384
#define C_DIM 1536
#define NBATCH 32
#define NKT 24            // 1536/64 K-tiles (BK=64)
#define NMT 128           // 16384/128 memory tiles
#define FINF 3.4e38f

__device__ __forceinline__ u16 f2bf(float x){           // RTNE fp32->bf16
  unsigned u = __float_as_uint(x);
  u += 0x7fffu + ((u >> 16) & 1u);
  return (u16)(u >> 16);
}
__device__ __forceinline__ float bf2f(u16 h){
  return __uint_as_float(((unsigned)h) << 16);
}

#define GLDS16(g, l) __builtin_amdgcn_global_load_lds( \
    (const __attribute__((address_space(1))) void*)(g), \
    (__attribute__((address_space(3))) void*)(l), 16, 0, 0)

// ---------------------------------------------------------------------------
// 1) fp32 -> bf16 copy + exact fp32 row norms. 1 wave per row, 4 rows/block.
// ---------------------------------------------------------------------------
__global__ __launch_bounds__(256) void conv_norm_k(const float* __restrict__ in,
                                                   u16* __restrict__ ob,
                                                   float* __restrict__ nrm){
  int row  = blockIdx.x*4 + (threadIdx.x>>6);
  int lane = threadIdx.x & 63;
  const float* r = in + (size_t)row*C_DIM;
  u16* o = ob + (size_t)row*C_DIM;
  float s = 0.f;
  #pragma unroll
  for (int i=0;i<6;++i){
    int idx = i*256 + lane*4;
    float4 v = *(const float4*)(r + idx);
    s += v.x*v.x + v.y*v.y + v.z*v.z + v.w*v.w;
    u16x4 u; u.x=f2bf(v.x); u.y=f2bf(v.y); u.z=f2bf(v.z); u.w=f2bf(v.w);
    *(u16x4*)(o + idx) = u;
  }
  #pragma unroll
  for (int m=32;m;m>>=1) s += __shfl_xor(s, m);
  if (lane==0) nrm[row] = s;
}

// ---------------------------------------------------------------------------
// 2) 128x128 bf16 MFMA distance + fused per-row min/argmin per tile.
//    m97 structure: 4 waves (2x2, 64x64 out each), BK=64, single 32 KiB LDS
//    buffer, __syncthreads-only sync, NO launch-bounds min (let regalloc
//    land ~3 blocks/CU -> 12 waves/CU implicit cross-block overlap, m114).
//    k-major LDS [kk][row][32] + verified 0-conflict swizzle.
// ---------------------------------------------------------------------------
__global__ __launch_bounds__(256) void dist128_k(const u16* __restrict__ fb,
                                                 const u16* __restrict__ mb,
                                                 const float* __restrict__ fn,
                                                 const float* __restrict__ mn,
                                                 float* __restrict__ pmin,
                                                 int* __restrict__ pidx){
  __shared__ u16 lds[16384];          // 32 KiB: A [2][128][32] + B at +8192
  const int tid = threadIdx.x;
  const int bid = blockIdx.x;
  // bijective XCD remap: li -> (ntHi, mtl, ntLo); 16 mt x 4-nt groups per XCD
  const int xcd = bid & 7;
  const int li  = bid >> 3;                     // 0..1023
  const int nt  = ((li >> 6) << 2) | (li & 3);  // 0..63 feature tile
  const int mt  = (xcd << 4) | ((li >> 2) & 15);// 0..127 memory tile
  const int wid = tid >> 6, lane = tid & 63;
  const int wm = wid >> 1, wn = wid & 1;        // 2x2 waves, each 64x64 out
  const int lr = lane & 15, lk = lane >> 4;
  const int slk8 = (lk ^ ((lr >> 1) & 3)) * 8;  // swizzled read chunk (u16)
  const int sgc  = (tid & 3) ^ ((tid >> 3) & 3);// pre-swizzled source chunk
  const int arow0 = nt*128, brow0 = mt*128;

  // one issue = 64 rows x 32 k (4 KiB). A per kt = 4 issues, B = 4.
#define ISSUE_A(kt, kk, h) GLDS16( \
    fb + (size_t)(arow0 + (h)*64 + (tid>>2))*C_DIM + (kt)*64 + (kk)*32 + sgc*8, \
    lds + (kk)*4096 + (h)*2048 + tid*8)
#define ISSUE_B(kt, kk, h) GLDS16( \
    mb + (size_t)(brow0 + (h)*64 + (tid>>2))*C_DIM + (kt)*64 + (kk)*32 + sgc*8, \
    lds + 8192 + (kk)*4096 + (h)*2048 + tid*8)
#define LDA(kk, row) (*(const bf16x8*)(lds + (kk)*4096 + (row)*32 + slk8))
#define LDB(kk, row) (*(const bf16x8*)(lds + 8192 + (kk)*4096 + (row)*32 + slk8))

  f32x4 acc[4][4];
  #pragma unroll
  for (int m=0;m<4;++m)
    #pragma unroll
    for (int n=0;n<4;++n) acc[m][n] = (f32x4){0.f,0.f,0.f,0.f};

  for (int u=0; u<NKT; ++u){
    ISSUE_A(u,0,0); ISSUE_A(u,0,1); ISSUE_A(u,1,0); ISSUE_A(u,1,1);
    ISSUE_B(u,0,0); ISSUE_B(u,0,1); ISSUE_B(u,1,0); ISSUE_B(u,1,1);
    __syncthreads();                 // drains vmcnt/lgkm + barrier (m97 style)
    #pragma unroll
    for (int kk=0; kk<2; ++kk){
      bf16x8 av[4], bv[4];
      #pragma unroll
      for (int m=0;m<4;++m) av[m] = LDA(kk, wm*64 + m*16 + lr);
      #pragma unroll
      for (int n=0;n<4;++n) bv[n] = LDB(kk, wn*64 + n*16 + lr);
      #pragma unroll
      for (int m=0;m<4;++m)
        #pragma unroll
        for (int n=0;n<4;++n)
          acc[m][n] = __builtin_amdgcn_mfma_f32_16x16x32_bf16(av[m], bv[n], acc[m][n],0,0,0);
    }
    __syncthreads();                 // frag reads done before next overwrite
  }

  // epilogue: d = sqrt(max(fa + mb - 2ab, 0)); min/argmin over 128 cols.
  // C/D frag layout: col = lane&15, row = (lane>>4)*4 + reg
  const int rowbase = nt*128 + wm*64;
  const int colbase = mt*128 + wn*64;
  float mnv[4];
  #pragma unroll
  for (int n=0;n<4;++n) mnv[n] = mn[colbase + n*16 + lr];
  float minv[16]; int mini[16];
  #pragma unroll
  for (int m=0;m<4;++m){
    #pragma unroll
    for (int r=0;r<4;++r){
      float fa = fn[rowbase + m*16 + lk*4 + r];
      float mv = FINF; int mi = 0x7fffffff;
      #pragma unroll
      for (int n=0;n<4;++n){
        int ci = colbase + n*16 + lr;
        float d2 = fa + mnv[n] - 2.0f*acc[m][n][r];
        float d = sqrtf(fmaxf(d2, 0.0f));
        if (d < mv){ mv = d; mi = ci; }
      }
      minv[m*4+r] = mv; mini[m*4+r] = mi;
    }
  }
  #pragma unroll
  for (int msk=1; msk<16; msk<<=1){
    #pragma unroll
    for (int i=0;i<16;++i){
      float ov = __shfl_xor(minv[i], msk);
      int   oi = __shfl_xor(mini[i], msk);
      if (ov < minv[i] || (ov == minv[i] && oi < mini[i])){ minv[i]=ov; mini[i]=oi; }
    }
  }
  float* lm = (float*)lds;                   // [2][128]
  int*   li2 = (int*)((char*)lds + 2048);    // [2][128]
  int rowl = wm*64 + (lr>>2)*16 + lk*4 + (lr&3);
  lm[wn*128 + rowl] = minv[lr];
  li2[wn*128 + rowl] = mini[lr];
  __syncthreads();
  if (tid < 128){
    float v0=lm[tid], v1=lm[128+tid];
    int   i0=li2[tid], i1=li2[128+tid];
    if (v1 < v0 || (v1==v0 && i1<i0)){ v0=v1; i0=i1; }
    size_t o = (size_t)(nt*128 + tid)*NMT + mt;
    pmin[o]=v0; pidx[o]=i0;
  }
#undef ISSUE_A
#undef ISSUE_B
#undef LDA
#undef LDB
}

// ---------------------------------------------------------------------------
// 3) refine: exact fp32 distance for candidates within band of bf16 min
//    -> exact nn_dists / nn_indices (selection-exact vs reference).
// ---------------------------------------------------------------------------
__global__ __launch_bounds__(256) void refine_k(const float* __restrict__ feat,
                                                const float* __restrict__ memf,
                                                const float* __restrict__ fn,
                                                const float* __restrict__ mn,
                                                const float* __restrict__ pmin,
                                                const int* __restrict__ pidx,
                                                float* __restrict__ nnd,
                                                int* __restrict__ nni){
  int wid = threadIdx.x>>6, lane = threadIdx.x&63;
  int row = blockIdx.x*4 + wid;
  const float* pm = pmin + (size_t)row*NMT;
  const int*   pi = pidx + (size_t)row*NMT;
  float v0 = pm[lane], v1 = pm[64+lane];
  float mv = fminf(v0, v1);
  #pragma unroll
  for (int m=32;m;m>>=1) mv = fminf(mv, __shfl_xor(mv, m));
  float band = mv + 0.02f;   // covers bf16-GEMM error (~16 sigma)
  unsigned long long b0 = __ballot(v0 <= band);
  unsigned long long b1 = __ballot(v1 <= band);

  float fr[24];
  const float* f = feat + (size_t)row*C_DIM;
  #pragma unroll
  for (int i=0;i<6;++i){
    float4 t = *(const float4*)(f + i*256 + lane*4);
    fr[i*4+0]=t.x; fr[i*4+1]=t.y; fr[i*4+2]=t.z; fr[i*4+3]=t.w;
  }
  float fa = fn[row];
  float bd = FINF; int bi = 0x7fffffff;
  while (b0 | b1){                       // ascending tile => ascending idx
    int t;
    if (b0){ t = __ffsll(b0)-1; b0 &= b0-1; }
    else   { t = 64 + __ffsll(b1)-1; b1 &= b1-1; }
    int cidx = pi[t];
    const float* mrow = memf + (size_t)cidx*C_DIM;
    float acc = 0.f;
    #pragma unroll
    for (int i=0;i<6;++i){
      float4 m4 = *(const float4*)(mrow + i*256 + lane*4);
      acc += fr[i*4+0]*m4.x + fr[i*4+1]*m4.y + fr[i*4+2]*m4.z + fr[i*4+3]*m4.w;
    }
    #pragma unroll
    for (int m=32;m;m>>=1) acc += __shfl_xor(acc, m);
    float d = sqrtf(fmaxf(fa + mn[cidx] - 2.0f*acc, 0.f));
    if (d < bd || (d == bd && cidx < bi)){ bd = d; bi = cidx; }
  }
  if (lane==0){ nnd[row]=bd; nni[row]=bi; }
}

// ---------------------------------------------------------------------------
// 4) WT[i][y] = composite (gaussian-zero-pad o bilinear-halfpixel) weights
// ---------------------------------------------------------------------------
__global__ void build_WT(float* __restrict__ WT){
  int y = threadIdx.x;                 // 256 threads, 1 block
  float g[25]; float Z = 0.f;
  #pragma unroll
  for (int k=0;k<25;++k){ float x=(float)(k-12)*0.25f; g[k]=expf(-0.5f*x*x); Z+=g[k]; }
  float acc[16];
  #pragma unroll
  for (int i=0;i<16;++i) acc[i]=0.f;
  for (int dy=0; dy<25; ++dy){
    int yy = y - 12 + dy;
    if (yy < 0 || yy > 255) continue;
    float gg = g[dy]/Z;
    float src = ((float)yy + 0.5f)*0.0625f - 0.5f;
    int i0 = (int)floorf(src);
    float fz = src - (float)i0;
    if (i0 < 0){ i0 = 0; fz = 0.f; }
    else if (i0 >= 15){ i0 = 15; fz = 0.f; }
    acc[i0] += gg*(1.f-fz);
    if (fz > 0.f) acc[i0+1] += gg*fz;
  }
  for (int i=0;i<16;++i) WT[i*256 + y] = acc[i];
}

// ---------------------------------------------------------------------------
// 5) amap[b] = W ps[b] W^T  (separable; exact fp32)
// ---------------------------------------------------------------------------
__global__ __launch_bounds__(256) void amap_k(const float* __restrict__ nnd,
                                              const float* __restrict__ WT,
                                              float* __restrict__ out){
  __shared__ float ps[256];
  __shared__ float wt[16*256];
  __shared__ float tmp[16*256];
  int b = blockIdx.x, yc = blockIdx.y, t = threadIdx.x;
  ps[t] = nnd[b*256 + t];
  #pragma unroll
  for (int i=0;i<16;++i) wt[i*256+t] = WT[i*256+t];
  __syncthreads();
  #pragma unroll
  for (int i=0;i<16;++i){
    float s=0.f;
    #pragma unroll
    for (int j=0;j<16;++j) s += wt[j*256+t]*ps[i*16+j];
    tmp[i*256+t]=s;
  }
  __syncthreads();
  float* ob = out + ((size_t)b<<16) + yc*32*256 + t;
  for (int yy=0; yy<32; ++yy){
    int y = yc*32+yy;
    float s=0.f;
    #pragma unroll
    for (int i=0;i<16;++i) s += wt[i*256+y]*tmp[i*256+t];
    ob[(size_t)yy*256] = s;
  }
}

// ---------------------------------------------------------------------------
// 6) per-batch argmax of patch scores -> s_star, m_star_idx
// ---------------------------------------------------------------------------
__global__ void argmax_k(const float* __restrict__ nnd, const int* __restrict__ nni,
                         float* __restrict__ sstar, int* __restrict__ midx){
  int b=blockIdx.x, t=threadIdx.x, lane=t&63, wid=t>>6;
  float v = nnd[b*256+t]; int i=t;
  #pragma unroll
  for (int m=1;m<64;m<<=1){
    float ov=__shfl_xor(v,m); int oi=__shfl_xor(i,m);
    if (ov > v || (ov==v && oi<i)){ v=ov; i=oi; }
  }
  __shared__ float sv[4]; __shared__ int si[4];
  if (lane==0){ sv[wid]=v; si[wid]=i; }
  __syncthreads();
  if (t==0){
    for (int w=1;w<4;++w){ if (sv[w]>v || (sv[w]==v && si[w]<i)){ v=sv[w]; i=si[w]; } }
    sstar[b]=v; midx[b]=nni[b*256+i];
  }
}

// ---------------------------------------------------------------------------
// 7) m_dists: 32 m_star vectors (bf16, half staged in LDS) vs all memory rows
// ---------------------------------------------------------------------------
__global__ __launch_bounds__(256) void mdist_k(const u16* __restrict__ mb,
                                               const float* __restrict__ mn,
                                               const int* __restrict__ midx,
                                               float* __restrict__ dmat){
  __shared__ u16 ms[16*C_DIM];       // 48 KiB: stage 16 m_stars per half
  __shared__ int sidx[32]; __shared__ float snrm[32];
  int t = threadIdx.x;
  if (t < 32){ int r = midx[t]; sidx[t]=r; snrm[t]=mn[r]; }
  int wid=t>>6, lane=t&63;
  for (int h=0; h<2; ++h){
    __syncthreads();
    for (int c=t; c<3072; c+=256){     // 16 rows x 192 x 16B chunks
      int s = c/192, o = c - s*192;
      *(u16x8*)(&ms[s*C_DIM + o*8]) = *(const u16x8*)(mb + (size_t)sidx[h*16+s]*C_DIM + o*8);
    }
    __syncthreads();
    for (int v=0; v<16; ++v){
      int m = blockIdx.x*64 + wid*16 + v;
      const u16* row = mb + (size_t)m*C_DIM;
      float rf[24];
      #pragma unroll
      for (int i=0;i<3;++i){
        u16x8 rv = *(const u16x8*)(row + i*512 + lane*8);
        #pragma unroll
        for (int j=0;j<8;++j) rf[i*8+j] = bf2f(rv[j]);
      }
      float mnv = mn[m];
      for (int s=0;s<16;++s){
        float acc=0.f;
        #pragma unroll
        for (int i=0;i<3;++i){
          u16x8 w = *(const u16x8*)(&ms[s*C_DIM + i*512 + lane*8]);
          #pragma unroll
          for (int j=0;j<8;++j) acc += rf[i*8+j]*bf2f(w[j]);
        }
        #pragma unroll
        for (int msk=32;msk;msk>>=1) acc += __shfl_xor(acc, msk);
        if (lane==0)
          dmat[(size_t)(h*16+s)*M_MEM + m] = sqrtf(fmaxf(snrm[h*16+s] + mnv - 2.0f*acc, 0.f));
      }
    }
  }
}

// ---------------------------------------------------------------------------
// 8) per-batch top-10 smallest distances -> reweighted score
//    (parallel 4-level merge instead of single-thread 2560-scan)
// ---------------------------------------------------------------------------
__device__ __forceinline__ void top10_scan(const float* src, int n, float* tp){
  #pragma unroll
  for (int i=0;i<10;++i) tp[i]=FINF;
  for (int c=0;c<n;++c){
    float v=src[c];
    if (v < tp[9]){
      #pragma unroll
      for (int j=0;j<10;++j){ float lo=fminf(tp[j],v); v=fmaxf(tp[j],v); tp[j]=lo; }
    }
  }
}

__global__ __launch_bounds__(256) void score_k(const float* __restrict__ dmat,
                                               const float* __restrict__ sstar,
                                               float* __restrict__ out){
  int b=blockIdx.x, t=threadIdx.x;
  float top[10];
  #pragma unroll
  for (int i=0;i<10;++i) top[i]=FINF;
  for (int i=0;i<64;++i){
    float v = dmat[(size_t)b*M_MEM + i*256 + t];
    if (v < top[9]){
      #pragma unroll
      for (int j=0;j<10;++j){ float lo=fminf(top[j],v); v=fmaxf(top[j],v); top[j]=lo; }
    }
  }
  __shared__ float cand[2560];
  __shared__ float l1[640];
  __shared__ float l2[160];
  __shared__ float l3[40];
  #pragma unroll
  for (int i=0;i<10;++i) cand[t*10+i]=top[i];
  __syncthreads();
  if (t < 64){
    float tp[10]; top10_scan(&cand[t*40], 40, tp);
    #pragma unroll
    for (int i=0;i<10;++i) l1[t*10+i]=tp[i];
  }
  __syncthreads();
  if (t < 16){
    float tp[10]; top10_scan(&l1[t*40], 40, tp);
    #pragma unroll
    for (int i=0;i<10;++i) l2[t*10+i]=tp[i];
  }
  __syncthreads();
  if (t < 4){
    float tp[10]; top10_scan(&l2[t*40], 40, tp);
    #pragma unroll
    for (int i=0;i<10;++i) l3[t*10+i]=tp[i];
  }
  __syncthreads();
  if (t==0){
    float tp[10]; top10_scan(l3, 40, tp);
    // drop tp[0] (self); w = 1 - exp(d1)/sum = 1 - 1/sum(exp(di-d1))
    float d1 = tp[1];
    float ssum = 0.f;
    #pragma unroll
    for (int i=1;i<10;++i) ssum += expf(tp[i]-d1);
    out[b] = (1.0f - 1.0f/ssum) * sstar[b];
  }
}

// ---------------------------------------------------------------------------
extern "C" void kernel_launch(void* const* d_in, const int* in_sizes, int n_in,
                              void* d_out, int out_size, void* d_ws, size_t ws_size,
                              hipStream_t stream){
  const float* feat = (const float*)d_in[0];
  const float* memf = (const float*)d_in[1];
  float* out = (float*)d_out;
  char* ws = (char*)d_ws;

  size_t o_fb = 0;
  size_t o_mb = o_fb + (size_t)N_FEAT*C_DIM*2;
  size_t o_fn = o_mb + (size_t)M_MEM*C_DIM*2;
  size_t o_mn = o_fn + (size_t)N_FEAT*4;
  size_t o_pv = o_mn + (size_t)M_MEM*4;
  size_t o_pi = o_pv + (size_t)N_FEAT*NMT*4;
  size_t o_nd = o_pi + (size_t)N_FEAT*NMT*4;
  size_t o_ni = o_nd + (size_t)N_FEAT*4;
  size_t o_wt = o_ni + (size_t)N_FEAT*4;
  size_t o_ss = o_wt + (size_t)16*256*4;
  size_t o_mi = o_ss + (size_t)NBATCH*4;
  size_t o_dm = o_mi + (size_t)NBATCH*4;
  size_t need = o_dm + (size_t)NBATCH*M_MEM*4;
  if (ws_size < need) return;

  u16*   fb  = (u16*)(ws+o_fb);
  u16*   mb  = (u16*)(ws+o_mb);
  float* fn  = (float*)(ws+o_fn);
  float* mn  = (float*)(ws+o_mn);
  float* pv  = (float*)(ws+o_pv);
  int*   pi  = (int*)(ws+o_pi);
  float* nd  = (float*)(ws+o_nd);
  int*   ni  = (int*)(ws+o_ni);
  float* wt  = (float*)(ws+o_wt);
  float* ss  = (float*)(ws+o_ss);
  int*   mi  = (int*)(ws+o_mi);
  float* dm  = (float*)(ws+o_dm);

  conv_norm_k<<<N_FEAT/4, 256, 0, stream>>>(feat, fb, fn);
  conv_norm_k<<<M_MEM/4, 256, 0, stream>>>(memf, mb, mn);
  dist128_k<<<8192, 256, 0, stream>>>(fb, mb, fn, mn, pv, pi);
  refine_k<<<N_FEAT/4, 256, 0, stream>>>(feat, memf, fn, mn, pv, pi, nd, ni);
  build_WT<<<1, 256, 0, stream>>>(wt);
  argmax_k<<<NBATCH, 256, 0, stream>>>(nd, ni, ss, mi);
  mdist_k<<<M_MEM/64, 256, 0, stream>>>(mb, mn, mi, dm);
  amap_k<<<dim3(NBATCH, 8), 256, 0, stream>>>(nd, wt, out + 32);
  score_k<<<NBATCH, 256, 0, stream>>>(dm, ss, out);
}